// Round 9
// baseline (552.982 us; speedup 1.0000x reference)
//
#include <hip/hip_runtime.h>
#include <hip/hip_fp16.h>
#include <cmath>

typedef _Float16 half8 __attribute__((ext_vector_type(8)));
typedef _Float16 half4_t __attribute__((ext_vector_type(4)));
typedef float f32x4 __attribute__((ext_vector_type(4)));

#define LDIM 4096
#define DDIM 1024
#define NSTATE 16
#define NCHUNK 128
#define CLEN 32
#define NBLK 512   // fused-scan grid; co-resident at 2 blocks/CU

#define GLD16(g, l) __builtin_amdgcn_global_load_lds( \
    (const __attribute__((address_space(1))) void*)(g), \
    (__attribute__((address_space(3))) void*)(l), 16, 0, 0)

// coherent-path accessors for data crossing block boundaries WITHIN a kernel
__device__ inline void at_store_f(float* p, float v) {
  __hip_atomic_store(p, v, __ATOMIC_RELAXED, __HIP_MEMORY_SCOPE_AGENT);
}
__device__ inline float at_load_f(const float* p) {
  return __hip_atomic_load(p, __ATOMIC_RELAXED, __HIP_MEMORY_SCOPE_AGENT);
}
__device__ inline void at_store_f2(float2* p, float2 v) {
  unsigned long long b; __builtin_memcpy(&b, &v, 8);
  __hip_atomic_store((unsigned long long*)p, b, __ATOMIC_RELAXED, __HIP_MEMORY_SCOPE_AGENT);
}
__device__ inline float2 at_load_f2(const float2* p) {
  unsigned long long b = __hip_atomic_load((const unsigned long long*)p,
                                           __ATOMIC_RELAXED, __HIP_MEMORY_SCOPE_AGENT);
  float2 v; __builtin_memcpy(&v, &b, 8); return v;
}

// grid barrier: single-use counter (zeroed by k_prep_norm each launch).
// Safe because all NBLK blocks are co-resident (VGPR<=128 via launch_bounds).
__device__ inline void gbar(unsigned int* cnt) {
  __threadfence();
  __syncthreads();
  if (threadIdx.x == 0) {
    __hip_atomic_fetch_add(cnt, 1u, __ATOMIC_ACQ_REL, __HIP_MEMORY_SCOPE_AGENT);
    while (__hip_atomic_load(cnt, __ATOMIC_ACQUIRE, __HIP_MEMORY_SCOPE_AGENT) < NBLK)
      __builtin_amdgcn_s_sleep(2);
  }
  __syncthreads();
  __threadfence();
}

// ---------------- K1: prep (W transpose + BC pack) + RMSNorm + zero bpc/bar ----------------
__global__ __launch_bounds__(256) void k_prep_norm(const float* __restrict__ x,
                                                   const float* __restrict__ nw,
                                                   const float* __restrict__ W,
                                                   const float* __restrict__ WB,
                                                   const float* __restrict__ WC,
                                                   _Float16* __restrict__ xnh,
                                                   _Float16* __restrict__ Wt,
                                                   _Float16* __restrict__ BCe,
                                                   float* __restrict__ bpc,
                                                   unsigned int* __restrict__ bar) {
  const int b = blockIdx.x, t = threadIdx.x;
  if (b < 4096) {
    const int l = b;
    if (t < 32) bpc[(size_t)l * 32 + t] = 0.f;      // zero BC accumulator
    float4 v = ((const float4*)(x + (size_t)l * DDIM))[t];
    float ss = v.x * v.x + v.y * v.y + v.z * v.z + v.w * v.w;
#pragma unroll
    for (int off = 32; off; off >>= 1) ss += __shfl_xor(ss, off, 64);
    __shared__ float sred[4];
    if ((t & 63) == 0) sred[t >> 6] = ss;
    __syncthreads();
    float tot = sred[0] + sred[1] + sred[2] + sred[3];
    float r = rsqrtf(tot * (1.0f / (float)DDIM) + 1e-6f);
    float4 wv = ((const float4*)nw)[t];
    half4_t h;
    h[0] = (_Float16)(v.x * wv.x * r); h[1] = (_Float16)(v.y * wv.y * r);
    h[2] = (_Float16)(v.z * wv.z * r); h[3] = (_Float16)(v.w * wv.w * r);
    ((half4_t*)(xnh + (size_t)l * DDIM))[t] = h;
  } else if (b < 4352) {
    if (b == 4096 && t < 4) bar[t] = 0u;            // zero barrier counters
    __shared__ float tile[64][65];
    const int bb = b - 4096;
    const int n0 = (bb & 15) * 64, k0 = (bb >> 4) * 64;
#pragma unroll
    for (int i = 0; i < 16; ++i) {
      int idx = t + i * 256;
      int kk = idx >> 6, nn = idx & 63;
      tile[kk][nn] = W[(size_t)(k0 + kk) * DDIM + n0 + nn];
    }
    __syncthreads();
#pragma unroll
    for (int i = 0; i < 16; ++i) {
      int idx = t + i * 256;
      int nn = idx >> 6, kk = idx & 63;
      Wt[(size_t)(n0 + nn) * DDIM + k0 + kk] = (_Float16)tile[kk][nn];
    }
  } else {
    const int by2 = b - 4352;
#pragma unroll
    for (int rr = 0; rr < 2; ++rr) {
      int r = 2 * by2 + rr;
      const float* src = (r & 1) ? WC : WB;
      int n = r >> 1;
#pragma unroll
      for (int j = 0; j < 4; ++j) {
        int k = t * 4 + j;
        BCe[(size_t)r * DDIM + k] = (_Float16)src[(size_t)k * NSTATE + n];
      }
    }
  }
}

// ---------------- K2: GEMM 128x128 + fused BC K-slices (r8, unchanged) ----------------
__global__ __launch_bounds__(256) void k_gemm128(const _Float16* __restrict__ Ah,
                                                 const _Float16* __restrict__ Bh,
                                                 const _Float16* __restrict__ B2h,
                                                 const float* __restrict__ b_delta,
                                                 _Float16* __restrict__ sdh,
                                                 float* __restrict__ bpc) {
  __shared__ __align__(16) _Float16 As[2][128 * 32];
  __shared__ __align__(16) _Float16 Bs[2][128 * 32];
  __shared__ __align__(16) _Float16 B2s[2][32 * 32];
  const int t = threadIdx.x;
  const int w = t >> 6, lane = t & 63;
  const int quad = lane >> 4, l16 = lane & 15;
  const int wr = w >> 1, wc = w & 1;
  const int bx = blockIdx.x, by = blockIdx.y;
  const int tileM = by * 128, tileN = bx * 128;
  const int srow = lane >> 2, scol = (lane & 3) * 8;
  const _Float16* gA0 = Ah + (size_t)(tileM + w * 32 + srow) * DDIM + scol;
  const _Float16* gB0 = Bh + (size_t)(tileN + w * 32 + srow) * DDIM + scol;
  const _Float16* gC0 = B2h + (size_t)(w * 16 + srow) * DDIM + scol;  // w<2 only

  f32x4 acc[4][4], acc2[4];
#pragma unroll
  for (int i = 0; i < 4; ++i) {
    acc2[i] = (f32x4){0.f, 0.f, 0.f, 0.f};
#pragma unroll
    for (int j = 0; j < 4; ++j) acc[i][j] = (f32x4){0.f, 0.f, 0.f, 0.f};
  }

  auto stage = [&](int kt, int p) {
    const int ko = kt * 32;
    GLD16(gA0 + ko,             &As[p][(w * 32) * 32]);
    GLD16(gA0 + 16 * DDIM + ko, &As[p][(w * 32 + 16) * 32]);
    GLD16(gB0 + ko,             &Bs[p][(w * 32) * 32]);
    GLD16(gB0 + 16 * DDIM + ko, &Bs[p][(w * 32 + 16) * 32]);
    if ((kt >> 2) == bx && w < 2)
      GLD16(gC0 + ko,           &B2s[p][(w * 16) * 32]);
  };

  stage(0, 0);
  for (int kt = 0; kt < 32; ++kt) {
    const int p = kt & 1;
    __syncthreads();
    if (kt < 31) stage(kt + 1, p ^ 1);
    half8 af[4], bf[4];
#pragma unroll
    for (int i = 0; i < 4; ++i)
      af[i] = *(const half8*)&As[p][(wr * 64 + i * 16 + l16) * 32 + quad * 8];
#pragma unroll
    for (int j = 0; j < 4; ++j)
      bf[j] = *(const half8*)&Bs[p][(wc * 64 + j * 16 + l16) * 32 + quad * 8];
#pragma unroll
    for (int i = 0; i < 4; ++i)
#pragma unroll
      for (int j = 0; j < 4; ++j)
        acc[i][j] = __builtin_amdgcn_mfma_f32_16x16x32_f16(af[i], bf[j], acc[i][j], 0, 0, 0);
    if ((kt >> 2) == bx) {
      half8 cf = *(const half8*)&B2s[p][(wc * 16 + l16) * 32 + quad * 8];
#pragma unroll
      for (int i = 0; i < 4; ++i)
        acc2[i] = __builtin_amdgcn_mfma_f32_16x16x32_f16(af[i], cf, acc2[i], 0, 0, 0);
    }
  }

  const float cC = 5.00005f, cH = 4.99995f, invH = 1.0f / 4.99995f;
  float bdl[4];
#pragma unroll
  for (int j = 0; j < 4; ++j) bdl[j] = b_delta[tileN + wc * 64 + j * 16 + l16];
#pragma unroll
  for (int i = 0; i < 4; ++i) {
#pragma unroll
    for (int r = 0; r < 4; ++r) {
      int row = tileM + wr * 64 + i * 16 + quad * 4 + r;
#pragma unroll
      for (int j = 0; j < 4; ++j) {
        int col = tileN + wc * 64 + j * 16 + l16;
        float z = acc[i][j][r] + bdl[j];
        float e = __expf(-fabsf(z));
        float sp = fmaxf(z, 0.f) + __logf(1.0f + e);
        float tt = (sp - cC) * invH;
        float e2 = __expf(-2.0f * fabsf(tt));
        float th = copysignf((1.0f - e2) / (1.0f + e2), tt);
        float dt = fmaf(cH, th, cC);
        sdh[(size_t)row * DDIM + col] = (_Float16)sqrtf(dt);
      }
      atomicAdd(&bpc[(size_t)row * 32 + wc * 16 + l16], acc2[i][r]);
    }
  }
}

// ---------------- K3: fused scan1 + comb + scan2 (regular launch, own barrier) ----------------
// 512 blocks x 256 thr. Block (dq=bid&3, c=bid>>2). Streaming phases keep VGPR low
// (~60) so launch_bounds(256,2) guarantees 2 blocks/CU -> all 512 co-resident.
// Cross-block data inside this kernel (Ph, Hin) goes over relaxed agent atomics.
__global__ __launch_bounds__(256, 2) void k_scan_fused(const _Float16* __restrict__ sdh,
                                                       const _Float16* __restrict__ xnh,
                                                       const float* __restrict__ bpc,
                                                       const float* __restrict__ A_log,
                                                       const float* __restrict__ Dskip,
                                                       float2* __restrict__ Ph,
                                                       float* __restrict__ Hin,
                                                       float* __restrict__ y,
                                                       unsigned int* __restrict__ bar) {
  __shared__ float2 bcs[CLEN * NSTATE];
  const int t = threadIdx.x;
  const int bid = blockIdx.x;
  const int dq = bid & 3, c = bid >> 2;
  const int d = dq * 256 + t;

  // bcs from bpc (written by previous kernel -> ordinary loads OK); reused in S2.
#pragma unroll
  for (int u = t; u < CLEN * NSTATE; u += 256) {
    int l = u >> 4, n2 = (u & 15) * 2;
    bcs[u] = *(const float2*)&bpc[(size_t)(c * CLEN + l) * 32 + n2];
  }
  float halfA[NSTATE], h[NSTATE], P[NSTATE];
#pragma unroll
  for (int n = 0; n < NSTATE; ++n) {
    halfA[n] = -0.5f * __expf(A_log[d * NSTATE + n]);
    h[n] = 0.f; P[n] = 1.f;
  }
  __syncthreads();

  // ---- Phase S1: streaming local scan -> {P, h_end}
  {
    const _Float16* sdr = sdh + (size_t)c * CLEN * DDIM + d;
    const _Float16* xr = xnh + (size_t)c * CLEN * DDIM + d;
#pragma unroll 2
    for (int i = 0; i < CLEN; ++i) {
      float sdv = (float)sdr[(size_t)i * DDIM];
      float xv = (float)xr[(size_t)i * DDIM];
      float dsq = sdv * sdv;
      float sdx = sdv * xv;
#pragma unroll
      for (int n = 0; n < NSTATE; ++n) {
        float2 bc = bcs[i * NSTATE + n];
        float hd = dsq * halfA[n];
        float di = __builtin_amdgcn_rcpf(1.0f - hd);
        float ab = fmaf(hd, di, di);
        h[n] = fmaf(ab, h[n], sdx * bc.x * di);
        P[n] *= ab;
      }
    }
#pragma unroll
    for (int n = 0; n < NSTATE; ++n)
      at_store_f2(&Ph[((size_t)c * NSTATE + n) * DDIM + d], make_float2(P[n], h[n]));
  }

  gbar(bar + 0);

  // ---- Phase C: sequential combine (blocks 0..63)
  if (bid < 64) {
    const int g = bid * 256 + t;
    float H = 0.f;
    for (int cb = 0; cb < NCHUNK; cb += 8) {
      float2 ph[8];
#pragma unroll
      for (int u = 0; u < 8; ++u)
        ph[u] = at_load_f2(&Ph[(size_t)(cb + u) * (DDIM * NSTATE) + g]);
#pragma unroll
      for (int u = 0; u < 8; ++u) {
        at_store_f(&Hin[(size_t)(cb + u) * (DDIM * NSTATE) + g], H);
        H = fmaf(ph[u].x, H, ph[u].y);
      }
    }
  }

  gbar(bar + 1);

  // ---- Phase S2: streaming re-scan with true h0, emit y
  {
#pragma unroll
    for (int n = 0; n < NSTATE; ++n)
      h[n] = at_load_f(&Hin[(size_t)c * (DDIM * NSTATE) + n * DDIM + d]);
    const float dsk = Dskip[d];
    const _Float16* sdr = sdh + (size_t)c * CLEN * DDIM + d;
    const _Float16* xr = xnh + (size_t)c * CLEN * DDIM + d;
    float* yr = y + (size_t)c * CLEN * DDIM + d;
#pragma unroll 2
    for (int i = 0; i < CLEN; ++i) {
      float sdv = (float)sdr[(size_t)i * DDIM];
      float xv = (float)xr[(size_t)i * DDIM];
      float dsq = sdv * sdv;
      float sdx = sdv * xv;
      float acc = dsk * xv;
#pragma unroll
      for (int n = 0; n < NSTATE; ++n) {
        float2 bc = bcs[i * NSTATE + n];
        float hd = dsq * halfA[n];
        float di = __builtin_amdgcn_rcpf(1.0f - hd);
        float ab = fmaf(hd, di, di);
        h[n] = fmaf(ab, h[n], sdx * bc.x * di);
        acc = fmaf(bc.y, h[n], acc);
      }
      yr[(size_t)i * DDIM] = acc;
    }
  }
}

// ---------------- launch ----------------
extern "C" void kernel_launch(void* const* d_in, const int* in_sizes, int n_in,
                              void* d_out, int out_size, void* d_ws, size_t ws_size,
                              hipStream_t stream) {
  const float* x       = (const float*)d_in[0];
  const float* A_log   = (const float*)d_in[1];
  const float* W_delta = (const float*)d_in[2];
  const float* b_delta = (const float*)d_in[3];
  const float* W_B     = (const float*)d_in[4];
  const float* W_C     = (const float*)d_in[5];
  const float* D_skip  = (const float*)d_in[6];
  const float* norm_w  = (const float*)d_in[7];
  float* y = (float*)d_out;

  char* ws = (char*)d_ws;
  const size_t MB = 1024 * 1024;
  _Float16* xnh = (_Float16*)(ws);              //  8 MB xn f16
  _Float16* Wt  = (_Float16*)(ws + 8 * MB);     //  2 MB W_delta^T f16
  _Float16* BCe = (_Float16*)(ws + 10 * MB);    // 64 KB packed W_B/W_C f16
  _Float16* sdh = (_Float16*)(ws + 11 * MB);    //  8 MB sqrt(delta) f16
  float*    bpc = (float*)(ws + 19 * MB);       // 512 KB BC accumulator [4096][32]
  float2*   Ph  = (float2*)(ws + 20 * MB);      // 16 MB {prodA, h_end}
  float*    Hin = (float*)(ws + 36 * MB);       //  8 MB chunk-entry states
  unsigned int* bar = (unsigned int*)(ws + 44 * MB);  // barrier counters
  (void)ws_size; (void)in_sizes; (void)n_in; (void)out_size;

  hipLaunchKernelGGL(k_prep_norm, dim3(4368), dim3(256), 0, stream,
                     x, norm_w, W_delta, W_B, W_C, xnh, Wt, BCe, bpc, bar);
  hipLaunchKernelGGL(k_gemm128, dim3(8, 32), dim3(256), 0, stream,
                     xnh, Wt, BCe, b_delta, sdh, bpc);
  hipLaunchKernelGGL(k_scan_fused, dim3(NBLK), dim3(256), 0, stream,
                     sdh, xnh, bpc, A_log, D_skip, Ph, Hin, y, bar);
}

// Round 10
// 263.705 us; speedup vs baseline: 2.0970x; 2.0970x over previous
//
#include <hip/hip_runtime.h>
#include <hip/hip_fp16.h>
#include <cmath>

typedef _Float16 half8 __attribute__((ext_vector_type(8)));
typedef _Float16 half4_t __attribute__((ext_vector_type(4)));
typedef float f32x4 __attribute__((ext_vector_type(4)));

#define LDIM 4096
#define DDIM 1024
#define NSTATE 16
#define NCHUNK 128
#define CLEN 32
#define NBLK 512   // fused-scan grid; co-resident at 2 blocks/CU

#define GLD16(g, l) __builtin_amdgcn_global_load_lds( \
    (const __attribute__((address_space(1))) void*)(g), \
    (__attribute__((address_space(3))) void*)(l), 16, 0, 0)

// coherent-path accessors for data crossing block boundaries WITHIN a kernel
__device__ inline void at_store_f(float* p, float v) {
  __hip_atomic_store(p, v, __ATOMIC_RELAXED, __HIP_MEMORY_SCOPE_AGENT);
}
__device__ inline float at_load_f(const float* p) {
  return __hip_atomic_load(p, __ATOMIC_RELAXED, __HIP_MEMORY_SCOPE_AGENT);
}
__device__ inline void at_store_f2(float2* p, float2 v) {
  unsigned long long b; __builtin_memcpy(&b, &v, 8);
  __hip_atomic_store((unsigned long long*)p, b, __ATOMIC_RELAXED, __HIP_MEMORY_SCOPE_AGENT);
}
__device__ inline float2 at_load_f2(const float2* p) {
  unsigned long long b = __hip_atomic_load((const unsigned long long*)p,
                                           __ATOMIC_RELAXED, __HIP_MEMORY_SCOPE_AGENT);
  float2 v; __builtin_memcpy(&v, &b, 8); return v;
}

// grid barrier, storm-free protocol:
//  - __syncthreads() drains the block's outstanding (LLC-coherent) stores
//  - arrival: one RELEASE fetch_add
//  - spin: RELAXED loads (NO per-iteration L2 invalidate!) + s_sleep throttle
//  - exit: one ACQUIRE load (single invalidate per block per barrier)
// r9's spin used ACQUIRE per iteration -> buffer_inv storm -> 158 GB/s collapse.
__device__ inline void gbar(unsigned int* cnt) {
  __syncthreads();
  if (threadIdx.x == 0) {
    __hip_atomic_fetch_add(cnt, 1u, __ATOMIC_RELEASE, __HIP_MEMORY_SCOPE_AGENT);
    while (__hip_atomic_load(cnt, __ATOMIC_RELAXED, __HIP_MEMORY_SCOPE_AGENT) < NBLK)
      __builtin_amdgcn_s_sleep(8);
    (void)__hip_atomic_load(cnt, __ATOMIC_ACQUIRE, __HIP_MEMORY_SCOPE_AGENT);
  }
  __syncthreads();
}

// ---------------- K1: prep (W transpose + BC pack) + RMSNorm + zero bpc/bar ----------------
__global__ __launch_bounds__(256) void k_prep_norm(const float* __restrict__ x,
                                                   const float* __restrict__ nw,
                                                   const float* __restrict__ W,
                                                   const float* __restrict__ WB,
                                                   const float* __restrict__ WC,
                                                   _Float16* __restrict__ xnh,
                                                   _Float16* __restrict__ Wt,
                                                   _Float16* __restrict__ BCe,
                                                   float* __restrict__ bpc,
                                                   unsigned int* __restrict__ bar) {
  const int b = blockIdx.x, t = threadIdx.x;
  if (b < 4096) {
    const int l = b;
    if (t < 32) bpc[(size_t)l * 32 + t] = 0.f;      // zero BC accumulator
    float4 v = ((const float4*)(x + (size_t)l * DDIM))[t];
    float ss = v.x * v.x + v.y * v.y + v.z * v.z + v.w * v.w;
#pragma unroll
    for (int off = 32; off; off >>= 1) ss += __shfl_xor(ss, off, 64);
    __shared__ float sred[4];
    if ((t & 63) == 0) sred[t >> 6] = ss;
    __syncthreads();
    float tot = sred[0] + sred[1] + sred[2] + sred[3];
    float r = rsqrtf(tot * (1.0f / (float)DDIM) + 1e-6f);
    float4 wv = ((const float4*)nw)[t];
    half4_t h;
    h[0] = (_Float16)(v.x * wv.x * r); h[1] = (_Float16)(v.y * wv.y * r);
    h[2] = (_Float16)(v.z * wv.z * r); h[3] = (_Float16)(v.w * wv.w * r);
    ((half4_t*)(xnh + (size_t)l * DDIM))[t] = h;
  } else if (b < 4352) {
    if (b == 4096 && t < 4) bar[t] = 0u;            // zero barrier counters
    __shared__ float tile[64][65];
    const int bb = b - 4096;
    const int n0 = (bb & 15) * 64, k0 = (bb >> 4) * 64;
#pragma unroll
    for (int i = 0; i < 16; ++i) {
      int idx = t + i * 256;
      int kk = idx >> 6, nn = idx & 63;
      tile[kk][nn] = W[(size_t)(k0 + kk) * DDIM + n0 + nn];
    }
    __syncthreads();
#pragma unroll
    for (int i = 0; i < 16; ++i) {
      int idx = t + i * 256;
      int nn = idx >> 6, kk = idx & 63;
      Wt[(size_t)(n0 + nn) * DDIM + k0 + kk] = (_Float16)tile[kk][nn];
    }
  } else {
    const int by2 = b - 4352;
#pragma unroll
    for (int rr = 0; rr < 2; ++rr) {
      int r = 2 * by2 + rr;
      const float* src = (r & 1) ? WC : WB;
      int n = r >> 1;
#pragma unroll
      for (int j = 0; j < 4; ++j) {
        int k = t * 4 + j;
        BCe[(size_t)r * DDIM + k] = (_Float16)src[(size_t)k * NSTATE + n];
      }
    }
  }
}

// ---------------- K2: GEMM 128x128 + fused BC K-slices (r8, unchanged) ----------------
__global__ __launch_bounds__(256) void k_gemm128(const _Float16* __restrict__ Ah,
                                                 const _Float16* __restrict__ Bh,
                                                 const _Float16* __restrict__ B2h,
                                                 const float* __restrict__ b_delta,
                                                 _Float16* __restrict__ sdh,
                                                 float* __restrict__ bpc) {
  __shared__ __align__(16) _Float16 As[2][128 * 32];
  __shared__ __align__(16) _Float16 Bs[2][128 * 32];
  __shared__ __align__(16) _Float16 B2s[2][32 * 32];
  const int t = threadIdx.x;
  const int w = t >> 6, lane = t & 63;
  const int quad = lane >> 4, l16 = lane & 15;
  const int wr = w >> 1, wc = w & 1;
  const int bx = blockIdx.x, by = blockIdx.y;
  const int tileM = by * 128, tileN = bx * 128;
  const int srow = lane >> 2, scol = (lane & 3) * 8;
  const _Float16* gA0 = Ah + (size_t)(tileM + w * 32 + srow) * DDIM + scol;
  const _Float16* gB0 = Bh + (size_t)(tileN + w * 32 + srow) * DDIM + scol;
  const _Float16* gC0 = B2h + (size_t)(w * 16 + srow) * DDIM + scol;  // w<2 only

  f32x4 acc[4][4], acc2[4];
#pragma unroll
  for (int i = 0; i < 4; ++i) {
    acc2[i] = (f32x4){0.f, 0.f, 0.f, 0.f};
#pragma unroll
    for (int j = 0; j < 4; ++j) acc[i][j] = (f32x4){0.f, 0.f, 0.f, 0.f};
  }

  auto stage = [&](int kt, int p) {
    const int ko = kt * 32;
    GLD16(gA0 + ko,             &As[p][(w * 32) * 32]);
    GLD16(gA0 + 16 * DDIM + ko, &As[p][(w * 32 + 16) * 32]);
    GLD16(gB0 + ko,             &Bs[p][(w * 32) * 32]);
    GLD16(gB0 + 16 * DDIM + ko, &Bs[p][(w * 32 + 16) * 32]);
    if ((kt >> 2) == bx && w < 2)
      GLD16(gC0 + ko,           &B2s[p][(w * 16) * 32]);
  };

  stage(0, 0);
  for (int kt = 0; kt < 32; ++kt) {
    const int p = kt & 1;
    __syncthreads();
    if (kt < 31) stage(kt + 1, p ^ 1);
    half8 af[4], bf[4];
#pragma unroll
    for (int i = 0; i < 4; ++i)
      af[i] = *(const half8*)&As[p][(wr * 64 + i * 16 + l16) * 32 + quad * 8];
#pragma unroll
    for (int j = 0; j < 4; ++j)
      bf[j] = *(const half8*)&Bs[p][(wc * 64 + j * 16 + l16) * 32 + quad * 8];
#pragma unroll
    for (int i = 0; i < 4; ++i)
#pragma unroll
      for (int j = 0; j < 4; ++j)
        acc[i][j] = __builtin_amdgcn_mfma_f32_16x16x32_f16(af[i], bf[j], acc[i][j], 0, 0, 0);
    if ((kt >> 2) == bx) {
      half8 cf = *(const half8*)&B2s[p][(wc * 16 + l16) * 32 + quad * 8];
#pragma unroll
      for (int i = 0; i < 4; ++i)
        acc2[i] = __builtin_amdgcn_mfma_f32_16x16x32_f16(af[i], cf, acc2[i], 0, 0, 0);
    }
  }

  const float cC = 5.00005f, cH = 4.99995f, invH = 1.0f / 4.99995f;
  float bdl[4];
#pragma unroll
  for (int j = 0; j < 4; ++j) bdl[j] = b_delta[tileN + wc * 64 + j * 16 + l16];
#pragma unroll
  for (int i = 0; i < 4; ++i) {
#pragma unroll
    for (int r = 0; r < 4; ++r) {
      int row = tileM + wr * 64 + i * 16 + quad * 4 + r;
#pragma unroll
      for (int j = 0; j < 4; ++j) {
        int col = tileN + wc * 64 + j * 16 + l16;
        float z = acc[i][j][r] + bdl[j];
        float e = __expf(-fabsf(z));
        float sp = fmaxf(z, 0.f) + __logf(1.0f + e);
        float tt = (sp - cC) * invH;
        float e2 = __expf(-2.0f * fabsf(tt));
        float th = copysignf((1.0f - e2) / (1.0f + e2), tt);
        float dt = fmaf(cH, th, cC);
        sdh[(size_t)row * DDIM + col] = (_Float16)sqrtf(dt);
      }
      atomicAdd(&bpc[(size_t)row * 32 + wc * 16 + l16], acc2[i][r]);
    }
  }
}

// ---------------- K3: fused scan1 + comb + scan2 (regular launch, own barrier) ----------------
__global__ __launch_bounds__(256, 2) void k_scan_fused(const _Float16* __restrict__ sdh,
                                                       const _Float16* __restrict__ xnh,
                                                       const float* __restrict__ bpc,
                                                       const float* __restrict__ A_log,
                                                       const float* __restrict__ Dskip,
                                                       float2* __restrict__ Ph,
                                                       float* __restrict__ Hin,
                                                       float* __restrict__ y,
                                                       unsigned int* __restrict__ bar) {
  __shared__ float2 bcs[CLEN * NSTATE];
  const int t = threadIdx.x;
  const int bid = blockIdx.x;
  const int dq = bid & 3, c = bid >> 2;
  const int d = dq * 256 + t;

  // bcs from bpc (written by previous kernel -> ordinary loads OK); reused in S2.
#pragma unroll
  for (int u = t; u < CLEN * NSTATE; u += 256) {
    int l = u >> 4, n2 = (u & 15) * 2;
    bcs[u] = *(const float2*)&bpc[(size_t)(c * CLEN + l) * 32 + n2];
  }
  float halfA[NSTATE], h[NSTATE], P[NSTATE];
#pragma unroll
  for (int n = 0; n < NSTATE; ++n) {
    halfA[n] = -0.5f * __expf(A_log[d * NSTATE + n]);
    h[n] = 0.f; P[n] = 1.f;
  }
  __syncthreads();

  // ---- Phase S1: streaming local scan -> {P, h_end}
  {
    const _Float16* sdr = sdh + (size_t)c * CLEN * DDIM + d;
    const _Float16* xr = xnh + (size_t)c * CLEN * DDIM + d;
#pragma unroll 2
    for (int i = 0; i < CLEN; ++i) {
      float sdv = (float)sdr[(size_t)i * DDIM];
      float xv = (float)xr[(size_t)i * DDIM];
      float dsq = sdv * sdv;
      float sdx = sdv * xv;
#pragma unroll
      for (int n = 0; n < NSTATE; ++n) {
        float2 bc = bcs[i * NSTATE + n];
        float hd = dsq * halfA[n];
        float di = __builtin_amdgcn_rcpf(1.0f - hd);
        float ab = fmaf(hd, di, di);
        h[n] = fmaf(ab, h[n], sdx * bc.x * di);
        P[n] *= ab;
      }
    }
#pragma unroll
    for (int n = 0; n < NSTATE; ++n)
      at_store_f2(&Ph[((size_t)c * NSTATE + n) * DDIM + d], make_float2(P[n], h[n]));
  }

  gbar(bar + 0);

  // ---- Phase C: sequential combine (blocks 0..63)
  if (bid < 64) {
    const int g = bid * 256 + t;
    float H = 0.f;
    for (int cb = 0; cb < NCHUNK; cb += 8) {
      float2 ph[8];
#pragma unroll
      for (int u = 0; u < 8; ++u)
        ph[u] = at_load_f2(&Ph[(size_t)(cb + u) * (DDIM * NSTATE) + g]);
#pragma unroll
      for (int u = 0; u < 8; ++u) {
        at_store_f(&Hin[(size_t)(cb + u) * (DDIM * NSTATE) + g], H);
        H = fmaf(ph[u].x, H, ph[u].y);
      }
    }
  }

  gbar(bar + 1);

  // ---- Phase S2: streaming re-scan with true h0, emit y
  {
#pragma unroll
    for (int n = 0; n < NSTATE; ++n)
      h[n] = at_load_f(&Hin[(size_t)c * (DDIM * NSTATE) + n * DDIM + d]);
    const float dsk = Dskip[d];
    const _Float16* sdr = sdh + (size_t)c * CLEN * DDIM + d;
    const _Float16* xr = xnh + (size_t)c * CLEN * DDIM + d;
    float* yr = y + (size_t)c * CLEN * DDIM + d;
#pragma unroll 2
    for (int i = 0; i < CLEN; ++i) {
      float sdv = (float)sdr[(size_t)i * DDIM];
      float xv = (float)xr[(size_t)i * DDIM];
      float dsq = sdv * sdv;
      float sdx = sdv * xv;
      float acc = dsk * xv;
#pragma unroll
      for (int n = 0; n < NSTATE; ++n) {
        float2 bc = bcs[i * NSTATE + n];
        float hd = dsq * halfA[n];
        float di = __builtin_amdgcn_rcpf(1.0f - hd);
        float ab = fmaf(hd, di, di);
        h[n] = fmaf(ab, h[n], sdx * bc.x * di);
        acc = fmaf(bc.y, h[n], acc);
      }
      yr[(size_t)i * DDIM] = acc;
    }
  }
}

// ---------------- launch ----------------
extern "C" void kernel_launch(void* const* d_in, const int* in_sizes, int n_in,
                              void* d_out, int out_size, void* d_ws, size_t ws_size,
                              hipStream_t stream) {
  const float* x       = (const float*)d_in[0];
  const float* A_log   = (const float*)d_in[1];
  const float* W_delta = (const float*)d_in[2];
  const float* b_delta = (const float*)d_in[3];
  const float* W_B     = (const float*)d_in[4];
  const float* W_C     = (const float*)d_in[5];
  const float* D_skip  = (const float*)d_in[6];
  const float* norm_w  = (const float*)d_in[7];
  float* y = (float*)d_out;

  char* ws = (char*)d_ws;
  const size_t MB = 1024 * 1024;
  _Float16* xnh = (_Float16*)(ws);              //  8 MB xn f16
  _Float16* Wt  = (_Float16*)(ws + 8 * MB);     //  2 MB W_delta^T f16
  _Float16* BCe = (_Float16*)(ws + 10 * MB);    // 64 KB packed W_B/W_C f16
  _Float16* sdh = (_Float16*)(ws + 11 * MB);    //  8 MB sqrt(delta) f16
  float*    bpc = (float*)(ws + 19 * MB);       // 512 KB BC accumulator [4096][32]
  float2*   Ph  = (float2*)(ws + 20 * MB);      // 16 MB {prodA, h_end}
  float*    Hin = (float*)(ws + 36 * MB);       //  8 MB chunk-entry states
  unsigned int* bar = (unsigned int*)(ws + 44 * MB);  // barrier counters
  (void)ws_size; (void)in_sizes; (void)n_in; (void)out_size;

  hipLaunchKernelGGL(k_prep_norm, dim3(4368), dim3(256), 0, stream,
                     x, norm_w, W_delta, W_B, W_C, xnh, Wt, BCe, bpc, bar);
  hipLaunchKernelGGL(k_gemm128, dim3(8, 32), dim3(256), 0, stream,
                     xnh, Wt, BCe, b_delta, sdh, bpc);
  hipLaunchKernelGGL(k_scan_fused, dim3(NBLK), dim3(256), 0, stream,
                     sdh, xnh, bpc, A_log, D_skip, Ph, Hin, y, bar);
}

// Round 11
// 241.156 us; speedup vs baseline: 2.2930x; 1.0935x over previous
//
#include <hip/hip_runtime.h>
#include <hip/hip_fp16.h>
#include <cmath>

typedef _Float16 half8 __attribute__((ext_vector_type(8)));
typedef _Float16 half4_t __attribute__((ext_vector_type(4)));
typedef float f32x4 __attribute__((ext_vector_type(4)));

#define LDIM 4096
#define DDIM 1024
#define NSTATE 16
#define NCHUNK 128
#define CLEN 32
#define NBLK 512   // fused-scan grid; co-resident at 2 blocks/CU

#define GLD16(g, l) __builtin_amdgcn_global_load_lds( \
    (const __attribute__((address_space(1))) void*)(g), \
    (__attribute__((address_space(3))) void*)(l), 16, 0, 0)

// coherent-path accessors for data crossing block boundaries WITHIN a kernel
__device__ inline void at_store_f(float* p, float v) {
  __hip_atomic_store(p, v, __ATOMIC_RELAXED, __HIP_MEMORY_SCOPE_AGENT);
}
__device__ inline float at_load_f(const float* p) {
  return __hip_atomic_load(p, __ATOMIC_RELAXED, __HIP_MEMORY_SCOPE_AGENT);
}
__device__ inline void at_store_f2(float2* p, float2 v) {
  unsigned long long b; __builtin_memcpy(&b, &v, 8);
  __hip_atomic_store((unsigned long long*)p, b, __ATOMIC_RELAXED, __HIP_MEMORY_SCOPE_AGENT);
}
__device__ inline float2 at_load_f2(const float2* p) {
  unsigned long long b = __hip_atomic_load((const unsigned long long*)p,
                                           __ATOMIC_RELAXED, __HIP_MEMORY_SCOPE_AGENT);
  float2 v; __builtin_memcpy(&v, &b, 8); return v;
}

// grid barrier, throttled spin:
// r9: ACQUIRE spin -> buffer_inv storm (453 us). r10: RELAXED spin at s_sleep(8)
// -> 512 threads x 1 bypass-load/~500cyc at ONE LLC line = fabric herd (153 us).
// r11: s_sleep(64) (~4K cyc) cuts herd rate 8x; wake cost <= ~1.7 us/barrier.
__device__ inline void gbar(unsigned int* cnt) {
  __syncthreads();
  if (threadIdx.x == 0) {
    __hip_atomic_fetch_add(cnt, 1u, __ATOMIC_RELEASE, __HIP_MEMORY_SCOPE_AGENT);
    while (__hip_atomic_load(cnt, __ATOMIC_RELAXED, __HIP_MEMORY_SCOPE_AGENT) < NBLK)
      __builtin_amdgcn_s_sleep(64);
    (void)__hip_atomic_load(cnt, __ATOMIC_ACQUIRE, __HIP_MEMORY_SCOPE_AGENT);
  }
  __syncthreads();
}

// ---------------- K1: prep (W transpose + BC pack) + RMSNorm + zero bpc/bar ----------------
__global__ __launch_bounds__(256) void k_prep_norm(const float* __restrict__ x,
                                                   const float* __restrict__ nw,
                                                   const float* __restrict__ W,
                                                   const float* __restrict__ WB,
                                                   const float* __restrict__ WC,
                                                   _Float16* __restrict__ xnh,
                                                   _Float16* __restrict__ Wt,
                                                   _Float16* __restrict__ BCe,
                                                   float* __restrict__ bpc,
                                                   unsigned int* __restrict__ bar) {
  const int b = blockIdx.x, t = threadIdx.x;
  if (b < 4096) {
    const int l = b;
    if (t < 32) bpc[(size_t)l * 32 + t] = 0.f;      // zero BC accumulator
    float4 v = ((const float4*)(x + (size_t)l * DDIM))[t];
    float ss = v.x * v.x + v.y * v.y + v.z * v.z + v.w * v.w;
#pragma unroll
    for (int off = 32; off; off >>= 1) ss += __shfl_xor(ss, off, 64);
    __shared__ float sred[4];
    if ((t & 63) == 0) sred[t >> 6] = ss;
    __syncthreads();
    float tot = sred[0] + sred[1] + sred[2] + sred[3];
    float r = rsqrtf(tot * (1.0f / (float)DDIM) + 1e-6f);
    float4 wv = ((const float4*)nw)[t];
    half4_t h;
    h[0] = (_Float16)(v.x * wv.x * r); h[1] = (_Float16)(v.y * wv.y * r);
    h[2] = (_Float16)(v.z * wv.z * r); h[3] = (_Float16)(v.w * wv.w * r);
    ((half4_t*)(xnh + (size_t)l * DDIM))[t] = h;
  } else if (b < 4352) {
    if (b == 4096 && t < 4) bar[t] = 0u;            // zero barrier counters
    __shared__ float tile[64][65];
    const int bb = b - 4096;
    const int n0 = (bb & 15) * 64, k0 = (bb >> 4) * 64;
#pragma unroll
    for (int i = 0; i < 16; ++i) {
      int idx = t + i * 256;
      int kk = idx >> 6, nn = idx & 63;
      tile[kk][nn] = W[(size_t)(k0 + kk) * DDIM + n0 + nn];
    }
    __syncthreads();
#pragma unroll
    for (int i = 0; i < 16; ++i) {
      int idx = t + i * 256;
      int nn = idx >> 6, kk = idx & 63;
      Wt[(size_t)(n0 + nn) * DDIM + k0 + kk] = (_Float16)tile[kk][nn];
    }
  } else {
    const int by2 = b - 4352;
#pragma unroll
    for (int rr = 0; rr < 2; ++rr) {
      int r = 2 * by2 + rr;
      const float* src = (r & 1) ? WC : WB;
      int n = r >> 1;
#pragma unroll
      for (int j = 0; j < 4; ++j) {
        int k = t * 4 + j;
        BCe[(size_t)r * DDIM + k] = (_Float16)src[(size_t)k * NSTATE + n];
      }
    }
  }
}

// ---------------- K2: GEMM 128x128 + fused BC K-slices (r8, unchanged) ----------------
__global__ __launch_bounds__(256) void k_gemm128(const _Float16* __restrict__ Ah,
                                                 const _Float16* __restrict__ Bh,
                                                 const _Float16* __restrict__ B2h,
                                                 const float* __restrict__ b_delta,
                                                 _Float16* __restrict__ sdh,
                                                 float* __restrict__ bpc) {
  __shared__ __align__(16) _Float16 As[2][128 * 32];
  __shared__ __align__(16) _Float16 Bs[2][128 * 32];
  __shared__ __align__(16) _Float16 B2s[2][32 * 32];
  const int t = threadIdx.x;
  const int w = t >> 6, lane = t & 63;
  const int quad = lane >> 4, l16 = lane & 15;
  const int wr = w >> 1, wc = w & 1;
  const int bx = blockIdx.x, by = blockIdx.y;
  const int tileM = by * 128, tileN = bx * 128;
  const int srow = lane >> 2, scol = (lane & 3) * 8;
  const _Float16* gA0 = Ah + (size_t)(tileM + w * 32 + srow) * DDIM + scol;
  const _Float16* gB0 = Bh + (size_t)(tileN + w * 32 + srow) * DDIM + scol;
  const _Float16* gC0 = B2h + (size_t)(w * 16 + srow) * DDIM + scol;  // w<2 only

  f32x4 acc[4][4], acc2[4];
#pragma unroll
  for (int i = 0; i < 4; ++i) {
    acc2[i] = (f32x4){0.f, 0.f, 0.f, 0.f};
#pragma unroll
    for (int j = 0; j < 4; ++j) acc[i][j] = (f32x4){0.f, 0.f, 0.f, 0.f};
  }

  auto stage = [&](int kt, int p) {
    const int ko = kt * 32;
    GLD16(gA0 + ko,             &As[p][(w * 32) * 32]);
    GLD16(gA0 + 16 * DDIM + ko, &As[p][(w * 32 + 16) * 32]);
    GLD16(gB0 + ko,             &Bs[p][(w * 32) * 32]);
    GLD16(gB0 + 16 * DDIM + ko, &Bs[p][(w * 32 + 16) * 32]);
    if ((kt >> 2) == bx && w < 2)
      GLD16(gC0 + ko,           &B2s[p][(w * 16) * 32]);
  };

  stage(0, 0);
  for (int kt = 0; kt < 32; ++kt) {
    const int p = kt & 1;
    __syncthreads();
    if (kt < 31) stage(kt + 1, p ^ 1);
    half8 af[4], bf[4];
#pragma unroll
    for (int i = 0; i < 4; ++i)
      af[i] = *(const half8*)&As[p][(wr * 64 + i * 16 + l16) * 32 + quad * 8];
#pragma unroll
    for (int j = 0; j < 4; ++j)
      bf[j] = *(const half8*)&Bs[p][(wc * 64 + j * 16 + l16) * 32 + quad * 8];
#pragma unroll
    for (int i = 0; i < 4; ++i)
#pragma unroll
      for (int j = 0; j < 4; ++j)
        acc[i][j] = __builtin_amdgcn_mfma_f32_16x16x32_f16(af[i], bf[j], acc[i][j], 0, 0, 0);
    if ((kt >> 2) == bx) {
      half8 cf = *(const half8*)&B2s[p][(wc * 16 + l16) * 32 + quad * 8];
#pragma unroll
      for (int i = 0; i < 4; ++i)
        acc2[i] = __builtin_amdgcn_mfma_f32_16x16x32_f16(af[i], cf, acc2[i], 0, 0, 0);
    }
  }

  const float cC = 5.00005f, cH = 4.99995f, invH = 1.0f / 4.99995f;
  float bdl[4];
#pragma unroll
  for (int j = 0; j < 4; ++j) bdl[j] = b_delta[tileN + wc * 64 + j * 16 + l16];
#pragma unroll
  for (int i = 0; i < 4; ++i) {
#pragma unroll
    for (int r = 0; r < 4; ++r) {
      int row = tileM + wr * 64 + i * 16 + quad * 4 + r;
#pragma unroll
      for (int j = 0; j < 4; ++j) {
        int col = tileN + wc * 64 + j * 16 + l16;
        float z = acc[i][j][r] + bdl[j];
        float e = __expf(-fabsf(z));
        float sp = fmaxf(z, 0.f) + __logf(1.0f + e);
        float tt = (sp - cC) * invH;
        float e2 = __expf(-2.0f * fabsf(tt));
        float th = copysignf((1.0f - e2) / (1.0f + e2), tt);
        float dt = fmaf(cH, th, cC);
        sdh[(size_t)row * DDIM + col] = (_Float16)sqrtf(dt);
      }
      atomicAdd(&bpc[(size_t)row * 32 + wc * 16 + l16], acc2[i][r]);
    }
  }
}

// ---------------- K3: fused scan1 + comb + scan2 ----------------
// 512 blocks x 256 thr, launch_bounds(256,2) -> 2 blocks/CU co-resident, VGPR cap 256.
// sarr/xarr cached in registers across S1 -> S2 (no 16 MB re-read).
__global__ __launch_bounds__(256, 2) void k_scan_fused(const _Float16* __restrict__ sdh,
                                                       const _Float16* __restrict__ xnh,
                                                       const float* __restrict__ bpc,
                                                       const float* __restrict__ A_log,
                                                       const float* __restrict__ Dskip,
                                                       float2* __restrict__ Ph,
                                                       float* __restrict__ Hin,
                                                       float* __restrict__ y,
                                                       unsigned int* __restrict__ bar) {
  __shared__ float2 bcs[CLEN * NSTATE];
  const int t = threadIdx.x;
  const int bid = blockIdx.x;
  const int dq = bid & 3, c = bid >> 2;
  const int d = dq * 256 + t;

  // bcs from bpc (written by previous kernel -> ordinary loads OK); reused in S2.
#pragma unroll
  for (int u = t; u < CLEN * NSTATE; u += 256) {
    int l = u >> 4, n2 = (u & 15) * 2;
    bcs[u] = *(const float2*)&bpc[(size_t)(c * CLEN + l) * 32 + n2];
  }
  float halfA[NSTATE], h[NSTATE], P[NSTATE];
#pragma unroll
  for (int n = 0; n < NSTATE; ++n) {
    halfA[n] = -0.5f * __expf(A_log[d * NSTATE + n]);
    h[n] = 0.f; P[n] = 1.f;
  }
  // load chunk's sd/xn once; retained in registers through S2
  float sarr[CLEN], xarr[CLEN];
  {
    const _Float16* sdr = sdh + (size_t)c * CLEN * DDIM + d;
    const _Float16* xr = xnh + (size_t)c * CLEN * DDIM + d;
#pragma unroll
    for (int i = 0; i < CLEN; ++i) {
      sarr[i] = (float)sdr[(size_t)i * DDIM];
      xarr[i] = (float)xr[(size_t)i * DDIM];
    }
  }
  __syncthreads();

  // ---- Phase S1: local scan -> {P, h_end}
#pragma unroll 2
  for (int i = 0; i < CLEN; ++i) {
    float dsq = sarr[i] * sarr[i];
    float sdx = sarr[i] * xarr[i];
#pragma unroll
    for (int n = 0; n < NSTATE; ++n) {
      float2 bc = bcs[i * NSTATE + n];
      float hd = dsq * halfA[n];
      float di = __builtin_amdgcn_rcpf(1.0f - hd);
      float ab = fmaf(hd, di, di);
      h[n] = fmaf(ab, h[n], sdx * bc.x * di);
      P[n] *= ab;
    }
  }
#pragma unroll
  for (int n = 0; n < NSTATE; ++n)
    at_store_f2(&Ph[((size_t)c * NSTATE + n) * DDIM + d], make_float2(P[n], h[n]));

  gbar(bar + 0);

  // ---- Phase C: sequential combine (blocks 0..63), 16-deep prefetch
  if (bid < 64) {
    const int g = bid * 256 + t;
    float H = 0.f;
    for (int cb = 0; cb < NCHUNK; cb += 16) {
      float2 ph[16];
#pragma unroll
      for (int u = 0; u < 16; ++u)
        ph[u] = at_load_f2(&Ph[(size_t)(cb + u) * (DDIM * NSTATE) + g]);
#pragma unroll
      for (int u = 0; u < 16; ++u) {
        at_store_f(&Hin[(size_t)(cb + u) * (DDIM * NSTATE) + g], H);
        H = fmaf(ph[u].x, H, ph[u].y);
      }
    }
  }

  gbar(bar + 1);

  // ---- Phase S2: re-scan with true h0 (register-cached inputs), emit y
  {
#pragma unroll
    for (int n = 0; n < NSTATE; ++n)
      h[n] = at_load_f(&Hin[(size_t)c * (DDIM * NSTATE) + n * DDIM + d]);
    const float dsk = Dskip[d];
    float* yr = y + (size_t)c * CLEN * DDIM + d;
#pragma unroll 2
    for (int i = 0; i < CLEN; ++i) {
      float dsq = sarr[i] * sarr[i];
      float sdx = sarr[i] * xarr[i];
      float acc = dsk * xarr[i];
#pragma unroll
      for (int n = 0; n < NSTATE; ++n) {
        float2 bc = bcs[i * NSTATE + n];
        float hd = dsq * halfA[n];
        float di = __builtin_amdgcn_rcpf(1.0f - hd);
        float ab = fmaf(hd, di, di);
        h[n] = fmaf(ab, h[n], sdx * bc.x * di);
        acc = fmaf(bc.y, h[n], acc);
      }
      yr[(size_t)i * DDIM] = acc;
    }
  }
}

// ---------------- launch ----------------
extern "C" void kernel_launch(void* const* d_in, const int* in_sizes, int n_in,
                              void* d_out, int out_size, void* d_ws, size_t ws_size,
                              hipStream_t stream) {
  const float* x       = (const float*)d_in[0];
  const float* A_log   = (const float*)d_in[1];
  const float* W_delta = (const float*)d_in[2];
  const float* b_delta = (const float*)d_in[3];
  const float* W_B     = (const float*)d_in[4];
  const float* W_C     = (const float*)d_in[5];
  const float* D_skip  = (const float*)d_in[6];
  const float* norm_w  = (const float*)d_in[7];
  float* y = (float*)d_out;

  char* ws = (char*)d_ws;
  const size_t MB = 1024 * 1024;
  _Float16* xnh = (_Float16*)(ws);              //  8 MB xn f16
  _Float16* Wt  = (_Float16*)(ws + 8 * MB);     //  2 MB W_delta^T f16
  _Float16* BCe = (_Float16*)(ws + 10 * MB);    // 64 KB packed W_B/W_C f16
  _Float16* sdh = (_Float16*)(ws + 11 * MB);    //  8 MB sqrt(delta) f16
  float*    bpc = (float*)(ws + 19 * MB);       // 512 KB BC accumulator [4096][32]
  float2*   Ph  = (float2*)(ws + 20 * MB);      // 16 MB {prodA, h_end}
  float*    Hin = (float*)(ws + 36 * MB);       //  8 MB chunk-entry states
  unsigned int* bar = (unsigned int*)(ws + 44 * MB);  // barrier counters
  (void)ws_size; (void)in_sizes; (void)n_in; (void)out_size;

  hipLaunchKernelGGL(k_prep_norm, dim3(4368), dim3(256), 0, stream,
                     x, norm_w, W_delta, W_B, W_C, xnh, Wt, BCe, bpc, bar);
  hipLaunchKernelGGL(k_gemm128, dim3(8, 32), dim3(256), 0, stream,
                     xnh, Wt, BCe, b_delta, sdh, bpc);
  hipLaunchKernelGGL(k_scan_fused, dim3(NBLK), dim3(256), 0, stream,
                     sdh, xnh, bpc, A_log, D_skip, Ph, Hin, y, bar);
}